// Round 4
// baseline (538.291 us; speedup 1.0000x reference)
//
#include <hip/hip_runtime.h>
#include <hip/hip_bf16.h>

#define KK 50      // triples per (b,t)
#define DD 100
#define TWO_D 200
#define DPAD 112   // padded output-feature dim (7 * 16)
#define KHT 224    // padded K for head_tail gemm (7 * 32)
#define KRL 128    // padded K for relation gemm (4 * 32)

// Unified per-row LDS X layout (bf16 elems): [0,232) head||tail (+8 dead pad),
// [232,360) relation, [360,376) dead. Pitch 376 elems = 752 B = 47*16 B:
// 16B-aligned b128 frag reads, row stride 47 (odd) 16B-units -> 2-way bank
// aliasing max (free per m136).
#define XPITCH 376
#define RLBASE 232

// workspace layout (bytes)
#define WS_WHT 256                       // bf16[DPAD*KHT]  = 50176 B
#define WS_WRL (WS_WHT + DPAD*KHT*2)     // bf16[DPAD*KRL]  = 28672 B
#define WS_BHT (WS_WRL + DPAD*KRL*2)     // bf16[DPAD]
#define WS_BRL (WS_BHT + 256)

typedef __attribute__((ext_vector_type(8))) short   s8v;
typedef __attribute__((ext_vector_type(8))) __bf16  b8v;
typedef __attribute__((ext_vector_type(4))) __bf16  b4v;
typedef __attribute__((ext_vector_type(4))) float   f32x4;

// --- MFMA shim: tolerate either builtin signature (short8 or bf16x8 operands) ---
template <typename T>
__device__ __forceinline__ auto mfma_try(T a, T b, f32x4 c, int)
    -> decltype(__builtin_amdgcn_mfma_f32_16x16x32_bf16(a, b, c, 0, 0, 0)) {
    return __builtin_amdgcn_mfma_f32_16x16x32_bf16(a, b, c, 0, 0, 0);
}
template <typename T, typename U = b8v>
__device__ __forceinline__ f32x4 mfma_try(T a, T b, f32x4 c, long) {
    U ab = __builtin_bit_cast(U, a);
    U bb = __builtin_bit_cast(U, b);
    return __builtin_amdgcn_mfma_f32_16x16x32_bf16(ab, bb, c, 0, 0, 0);
}
__device__ __forceinline__ f32x4 mfma16x16x32_bf16(s8v a, s8v b, f32x4 c) {
    return mfma_try(a, b, c, 0);
}

__device__ __forceinline__ float bf2f(__hip_bfloat16 h) { return __bfloat162float(h); }

__device__ __forceinline__ float tanh_fast(float x) {
    float e = __expf(2.f * x);
    return 1.f - 2.f * __builtin_amdgcn_rcpf(e + 1.f);
}

// ---------- prep: inline parallel dtype detection + weight canonicalization ----------
// fp32 read as two bf16 halves shows impossible exponents (data ~ N(0,0.02^2) -> |x|<256).
// int64 ids (< 2^32): odd int32 slots all zero; int32 ids uniform [0,5e5): ~none zero.
__global__ void prep_weights(const void* __restrict__ Wht, const void* __restrict__ bht,
                             const void* __restrict__ Wrl, const void* __restrict__ brl,
                             const unsigned int* __restrict__ embw,
                             const unsigned int* __restrict__ idsw,
                             void* __restrict__ ws) {
    __shared__ int sf[2];
    const int tid = threadIdx.x;

    if (tid < 64) {
        int bad = 0;
        #pragma unroll
        for (int i = 0; i < 16; i++) {
            unsigned int wv = embw[tid * 16 + i];
            unsigned int e0 = (wv >> 7)  & 0xFF;
            unsigned int e1 = (wv >> 23) & 0xFF;
            bad |= (e0 >= 0x87 || e1 >= 0x87) ? 1 : 0;
        }
        unsigned long long anyb = __ballot(bad != 0);
        int zero = (idsw[2 * tid + 1] == 0u) ? 1 : 0;
        unsigned long long zb = __ballot(zero != 0);
        if (tid == 0) {
            int f32 = anyb ? 1 : 0;
            int i64 = (__popcll(zb) >= 32) ? 1 : 0;
            sf[0] = f32; sf[1] = i64;
            ((int*)ws)[0] = f32;               // all prep blocks write identical values
            ((int*)ws)[1] = i64;
        }
    }
    __syncthreads();
    const bool f32 = sf[0] != 0;

    __hip_bfloat16* whtp = (__hip_bfloat16*)((char*)ws + WS_WHT);
    __hip_bfloat16* wrlp = (__hip_bfloat16*)((char*)ws + WS_WRL);
    __hip_bfloat16* bhtp = (__hip_bfloat16*)((char*)ws + WS_BHT);
    __hip_bfloat16* brlp = (__hip_bfloat16*)((char*)ws + WS_BRL);

    const int gid = blockIdx.x * blockDim.x + tid;
    const int gs  = gridDim.x * blockDim.x;

    for (int i = gid; i < DPAD * KHT; i += gs) {
        int d = i / KHT, f = i - d * KHT;
        float v = 0.f;
        if (d < DD && f < TWO_D)
            v = f32 ? ((const float*)Wht)[d * TWO_D + f]
                    : bf2f(((const __hip_bfloat16*)Wht)[d * TWO_D + f]);
        whtp[i] = __float2bfloat16(v);
    }
    for (int i = gid; i < DPAD * KRL; i += gs) {
        int d = i / KRL, f = i - d * KRL;
        float v = 0.f;
        if (d < DD && f < DD)
            v = f32 ? ((const float*)Wrl)[d * DD + f]
                    : bf2f(((const __hip_bfloat16*)Wrl)[d * DD + f]);
        wrlp[i] = __float2bfloat16(v);
    }
    for (int i = gid; i < DPAD; i += gs) {
        float vh = 0.f, vr = 0.f;
        if (i < DD) {
            vh = f32 ? ((const float*)bht)[i] : bf2f(((const __hip_bfloat16*)bht)[i]);
            vr = f32 ? ((const float*)brl)[i] : bf2f(((const __hip_bfloat16*)brl)[i]);
        }
        bhtp[i] = __float2bfloat16(vh);
        brlp[i] = __float2bfloat16(vr);
    }
}

__global__ __launch_bounds__(256, 4) void fused_outer_encoder(
    const int* __restrict__ ids,              // int32 or int64 (flagged)
    const void* __restrict__ emb_raw,         // fp32 or bf16 (flagged), [V][DD]
    const void* __restrict__ ws,
    float* __restrict__ out)                  // [NBT][TWO_D] fp32
{
    __shared__ __hip_bfloat16 sX[51 * XPITCH];   // rows 0..49 data, row 50 = zeros
    __shared__ int   sIds[KK * 3];
    __shared__ float sE[KK];
    __shared__ float sAl[KK];

    const int* flags = (const int*)ws;
    const __hip_bfloat16* whtp = (const __hip_bfloat16*)((const char*)ws + WS_WHT);
    const __hip_bfloat16* wrlp = (const __hip_bfloat16*)((const char*)ws + WS_WRL);
    const __hip_bfloat16* bhtp = (const __hip_bfloat16*)((const char*)ws + WS_BHT);
    const __hip_bfloat16* brlp = (const __hip_bfloat16*)((const char*)ws + WS_BRL);

    const int tid = threadIdx.x;
    const int bt  = blockIdx.x;
    const bool f32      = flags[0] != 0;
    const int idsStride = flags[1] ? 2 : 1;

    // ---- ids -> LDS; zero only pad regions + the dedicated zero row ----
    if (tid < KK * 3) sIds[tid] = ids[(bt * (KK * 3) + tid) * idsStride];
    {
        unsigned int* sXw = (unsigned int*)sX;   // u32 pitch = 188
        for (int i = tid; i < 600; i += 256) {   // ht pad: elems [200,224) of rows 0..49
            int r = i / 12, j = i - r * 12;
            sXw[r * 188 + 100 + j] = 0u;
        }
        for (int i = tid; i < 700; i += 256) {   // rl pad: elems [332,360) of rows 0..49
            int r = i / 14, j = i - r * 14;
            sXw[r * 188 + 166 + j] = 0u;
        }
        for (int i = tid; i < 188; i += 256) sXw[50 * 188 + i] = 0u;   // zero row
    }
    __syncthreads();

    // ---- gather 150 emb rows -> LDS bf16; 3750 16B-chunk tasks, batched 8+7
    // deep so each wave keeps ~8 global loads in flight (MLP for HBM BW) ----
    if (f32) {
        const float* embf = (const float*)emb_raw;
        float4 va[8]; int dof[8];
        #pragma unroll
        for (int i = 0; i < 8; i++) {
            int c = tid + i * 256;               // < 2048 < 3750 always
            int seg = c / 25, off = (c - seg * 25) * 4;
            int r = seg / 3, wh = seg - r * 3;   // 0=head 1=relation 2=tail
            size_t id = (size_t)sIds[seg];
            va[i]  = *(const float4*)(embf + id * DD + off);
            dof[i] = r * XPITCH + ((wh == 1) ? (RLBASE + off) : ((wh ? DD : 0) + off));
        }
        #pragma unroll
        for (int i = 0; i < 8; i++) {
            b4v pk = { (__bf16)va[i].x, (__bf16)va[i].y, (__bf16)va[i].z, (__bf16)va[i].w };
            *(b4v*)(sX + dof[i]) = pk;
        }
        float4 vb[7]; int dof2[7];
        #pragma unroll
        for (int i = 0; i < 7; i++) {
            int c = tid + (8 + i) * 256;
            bool ok = (c < KK * 3 * 25);
            int cc = ok ? c : 0;
            int seg = cc / 25, off = (cc - seg * 25) * 4;
            int r = seg / 3, wh = seg - r * 3;
            size_t id = (size_t)sIds[seg];
            if (ok) vb[i] = *(const float4*)(embf + id * DD + off);
            dof2[i] = ok ? (r * XPITCH + ((wh == 1) ? (RLBASE + off) : ((wh ? DD : 0) + off))) : -1;
        }
        #pragma unroll
        for (int i = 0; i < 7; i++) {
            if (dof2[i] >= 0) {
                b4v pk = { (__bf16)vb[i].x, (__bf16)vb[i].y, (__bf16)vb[i].z, (__bf16)vb[i].w };
                *(b4v*)(sX + dof2[i]) = pk;
            }
        }
    } else {
        const __hip_bfloat16* embh = (const __hip_bfloat16*)emb_raw;
        uint2 va[8]; int dof[8];
        #pragma unroll
        for (int i = 0; i < 8; i++) {
            int c = tid + i * 256;
            int seg = c / 25, off = (c - seg * 25) * 4;
            int r = seg / 3, wh = seg - r * 3;
            size_t id = (size_t)sIds[seg];
            va[i]  = *(const uint2*)(embh + id * DD + off);
            dof[i] = r * XPITCH + ((wh == 1) ? (RLBASE + off) : ((wh ? DD : 0) + off));
        }
        #pragma unroll
        for (int i = 0; i < 8; i++) *(uint2*)(sX + dof[i]) = va[i];
        uint2 vb[7]; int dof2[7];
        #pragma unroll
        for (int i = 0; i < 7; i++) {
            int c = tid + (8 + i) * 256;
            bool ok = (c < KK * 3 * 25);
            int cc = ok ? c : 0;
            int seg = cc / 25, off = (cc - seg * 25) * 4;
            int r = seg / 3, wh = seg - r * 3;
            size_t id = (size_t)sIds[seg];
            if (ok) vb[i] = *(const uint2*)(embh + id * DD + off);
            dof2[i] = ok ? (r * XPITCH + ((wh == 1) ? (RLBASE + off) : ((wh ? DD : 0) + off))) : -1;
        }
        #pragma unroll
        for (int i = 0; i < 7; i++)
            if (dof2[i] >= 0) *(uint2*)(sX + dof2[i]) = vb[i];
    }
    __syncthreads();

    const int lane = tid & 63;
    const int w    = tid >> 6;        // wave id: rows [w*16, w*16+16)
    const int n    = lane & 15;       // tile col (output feature selector)
    const int q    = lane >> 4;       // quad
    const int arow = w * 16 + n;
    const int arow2 = (arow < KK) ? arow : KK;   // clamp to dedicated zero row 50
    const __hip_bfloat16* abase = sX + arow2 * XPITCH;

    // ---- head_tail GEMM: K=224 (7 ksteps x 7 ntiles) ----
    f32x4 accH[7];
    #pragma unroll
    for (int t = 0; t < 7; t++) {
        #pragma unroll
        for (int j = 0; j < 4; j++) accH[t][j] = 0.f;
    }
    #pragma unroll
    for (int ks = 0; ks < 7; ks++) {
        s8v a = *(const s8v*)(abase + ks * 32 + q * 8);
        #pragma unroll
        for (int nt = 0; nt < 7; nt++) {
            s8v b = *(const s8v*)(whtp + (nt * 16 + n) * KHT + ks * 32 + q * 8);
            accH[nt] = mfma16x16x32_bf16(a, b, accH[nt]);
        }
    }

    float htv[7][4];
    #pragma unroll
    for (int nt = 0; nt < 7; nt++) {
        const float bias = bf2f(bhtp[nt * 16 + n]);
        #pragma unroll
        for (int j = 0; j < 4; j++) htv[nt][j] = tanh_fast(accH[nt][j] + bias);
    }

    // ---- relation GEMM: K=128 (4 ksteps x 7 ntiles) ----
    f32x4 accR[7];
    #pragma unroll
    for (int t = 0; t < 7; t++) {
        #pragma unroll
        for (int j = 0; j < 4; j++) accR[t][j] = 0.f;
    }
    #pragma unroll
    for (int ks = 0; ks < 4; ks++) {
        s8v a = *(const s8v*)(abase + RLBASE + ks * 32 + q * 8);
        #pragma unroll
        for (int nt = 0; nt < 7; nt++) {
            s8v b = *(const s8v*)(wrlp + (nt * 16 + n) * KRL + ks * 32 + q * 8);
            accR[nt] = mfma16x16x32_bf16(a, b, accR[nt]);
        }
    }

    // ---- e_weight: rowwise dot; reduce across the 16 n-lanes of each quad ----
    float dj[4];
    #pragma unroll
    for (int j = 0; j < 4; j++) dj[j] = 0.f;
    #pragma unroll
    for (int nt = 0; nt < 7; nt++) {
        const float bias = bf2f(brlp[nt * 16 + n]);
        #pragma unroll
        for (int j = 0; j < 4; j++) dj[j] += (accR[nt][j] + bias) * htv[nt][j];
    }
    #pragma unroll
    for (int mask = 1; mask < 16; mask <<= 1) {
        #pragma unroll
        for (int j = 0; j < 4; j++) dj[j] += __shfl_xor(dj[j], mask, 64);
    }
    if (n == 0) {
        #pragma unroll
        for (int j = 0; j < 4; j++) {
            const int kt = w * 16 + q * 4 + j;   // C/D row = quad*4 + reg
            if (kt < KK) sE[kt] = dj[j];
        }
    }
    __syncthreads();

    // ---- softmax over KK triples (wave 0) ----
    if (tid < 64) {
        float v = -3.0e38f;
        if (tid < KK) v = sE[tid];
        float mx = v;
        #pragma unroll
        for (int mask = 1; mask < 64; mask <<= 1) mx = fmaxf(mx, __shfl_xor(mx, mask, 64));
        float p = (tid < KK) ? __expf(v - mx) : 0.f;
        float s = p;
        #pragma unroll
        for (int mask = 1; mask < 64; mask <<= 1) s += __shfl_xor(s, mask, 64);
        if (tid < KK) sAl[tid] = p / s;
    }
    __syncthreads();

    // ---- output (fp32): re-gather head/tail rows from global at full precision
    // (rows are L2-hot: this block just staged them) ----
    if (tid < TWO_D) {
        const int half  = tid / DD;            // 0=head, 1=tail
        const int dmod  = tid - half * DD;
        const int whoff = half ? 2 : 0;
        float acc = 0.f;
        if (f32) {
            const float* embf = (const float*)emb_raw;
            #pragma unroll 10
            for (int k = 0; k < KK; k++) {
                size_t id = (size_t)sIds[k * 3 + whoff];
                acc += sAl[k] * embf[id * DD + dmod];
            }
        } else {
            const __hip_bfloat16* embh = (const __hip_bfloat16*)emb_raw;
            #pragma unroll 10
            for (int k = 0; k < KK; k++) {
                size_t id = (size_t)sIds[k * 3 + whoff];
                acc += sAl[k] * bf2f(embh[id * DD + dmod]);
            }
        }
        out[(size_t)bt * TWO_D + tid] = acc;
    }
}

extern "C" void kernel_launch(void* const* d_in, const int* in_sizes, int n_in,
                              void* d_out, int out_size, void* d_ws, size_t ws_size,
                              hipStream_t stream) {
    const int*  ids = (const int*)d_in[1];
    const void* emb = d_in[3];
    const void* Wht = d_in[4];
    const void* bht = d_in[5];
    const void* Wrl = d_in[6];
    const void* brl = d_in[7];
    float* out = (float*)d_out;

    const int nbt = in_sizes[1] / (KK * 3);   // B*T blocks

    hipLaunchKernelGGL(prep_weights, dim3(64), dim3(256), 0, stream,
                       Wht, bht, Wrl, brl,
                       (const unsigned int*)emb, (const unsigned int*)ids, d_ws);
    hipLaunchKernelGGL(fused_outer_encoder, dim3(nbt), dim3(256), 0, stream,
                       ids, emb, (const void*)d_ws, out);
}

// Round 6
// 537.141 us; speedup vs baseline: 1.0021x; 1.0021x over previous
//
#include <hip/hip_runtime.h>
#include <hip/hip_bf16.h>

#define KK 50      // triples per (b,t)
#define DD 100
#define TWO_D 200
#define DPAD 112   // padded output-feature dim (7 * 16)
#define KHT 224    // padded K for head_tail gemm (7 * 32)
#define KRL 128    // padded K for relation gemm (4 * 32)

// Unified per-row LDS X layout (fp16 elems): [0,232) head||tail (+8 dead pad),
// [232,360) relation data+pad, [360,376) dead. Pitch 376 elems = 752 B = 47*16B:
// 16B-aligned b128 frag reads; odd 16B-unit row stride -> <=2-way bank aliasing (free).
#define XPITCH 376
#define RLBASE 232

// workspace layout (bytes)
#define WS_WHT 256                        // fp16[DPAD*KHT] = 50176 B
#define WS_WRL (WS_WHT + DPAD*KHT*2)      // fp16[DPAD*KRL] = 28672 B
#define WS_BHT (WS_WRL + DPAD*KRL*2)      // float[DPAD] (512B slot)
#define WS_BRL (WS_BHT + 512)             // float[DPAD]
#define WS_TAB 262144                     // fp16[V*DD] packed (200 B rows)

typedef _Float16 half_t;
typedef __attribute__((ext_vector_type(8))) half_t h8v;
typedef __attribute__((ext_vector_type(4))) half_t h4v;
typedef __attribute__((ext_vector_type(8))) short  s8v;
typedef __attribute__((ext_vector_type(4))) float  f32x4;

// --- MFMA shim: tolerate either builtin signature (half8 or short8 operands) ---
template <typename T>
__device__ __forceinline__ auto mfma_f16_try(T a, T b, f32x4 c, int)
    -> decltype(__builtin_amdgcn_mfma_f32_16x16x32_f16(a, b, c, 0, 0, 0)) {
    return __builtin_amdgcn_mfma_f32_16x16x32_f16(a, b, c, 0, 0, 0);
}
template <typename T, typename U = s8v>
__device__ __forceinline__ f32x4 mfma_f16_try(T a, T b, f32x4 c, long) {
    U ab = __builtin_bit_cast(U, a);
    U bb = __builtin_bit_cast(U, b);
    return __builtin_amdgcn_mfma_f32_16x16x32_f16(ab, bb, c, 0, 0, 0);
}
__device__ __forceinline__ f32x4 mfma16x16x32_f16(h8v a, h8v b, f32x4 c) {
    return mfma_f16_try(a, b, c, 0);
}

__device__ __forceinline__ float bf2f(__hip_bfloat16 h) { return __bfloat162float(h); }
__device__ __forceinline__ float bfbits2f(unsigned int hi16) {
    return __builtin_bit_cast(float, hi16 << 16);
}

__device__ __forceinline__ float tanh_fast(float x) {
    float e = __expf(2.f * x);
    return 1.f - 2.f * __builtin_amdgcn_rcpf(e + 1.f);
}

// ---------- prep: parallel dtype detection + fp16 weight canonicalization ----------
// fp32 read as two bf16 halves shows impossible exponents (data ~ N(0,0.02^2) -> |x|<256).
// int64 ids (< 2^32): odd int32 slots all zero; int32 ids uniform [0,5e5): ~none zero.
__global__ void prep_weights(const void* __restrict__ Wht, const void* __restrict__ bht,
                             const void* __restrict__ Wrl, const void* __restrict__ brl,
                             const unsigned int* __restrict__ embw,
                             const unsigned int* __restrict__ idsw,
                             void* __restrict__ ws) {
    __shared__ int sf[2];
    const int tid = threadIdx.x;

    if (tid < 64) {
        int bad = 0;
        #pragma unroll
        for (int i = 0; i < 16; i++) {
            unsigned int wv = embw[tid * 16 + i];
            unsigned int e0 = (wv >> 7)  & 0xFF;
            unsigned int e1 = (wv >> 23) & 0xFF;
            bad |= (e0 >= 0x87 || e1 >= 0x87) ? 1 : 0;
        }
        unsigned long long anyb = __ballot(bad != 0);
        int zero = (idsw[2 * tid + 1] == 0u) ? 1 : 0;
        unsigned long long zb = __ballot(zero != 0);
        if (tid == 0) {
            sf[0] = anyb ? 1 : 0;
            sf[1] = (__popcll(zb) >= 32) ? 1 : 0;
            ((int*)ws)[0] = sf[0];
            ((int*)ws)[1] = sf[1];
        }
    }
    __syncthreads();
    const bool f32 = sf[0] != 0;

    half_t* whtp = (half_t*)((char*)ws + WS_WHT);
    half_t* wrlp = (half_t*)((char*)ws + WS_WRL);
    float*  bhtp = (float*)((char*)ws + WS_BHT);
    float*  brlp = (float*)((char*)ws + WS_BRL);

    const int gid = blockIdx.x * blockDim.x + tid;
    const int gs  = gridDim.x * blockDim.x;

    for (int i = gid; i < DPAD * KHT; i += gs) {
        int d = i / KHT, f = i - d * KHT;
        float v = 0.f;
        if (d < DD && f < TWO_D)
            v = f32 ? ((const float*)Wht)[d * TWO_D + f]
                    : bf2f(((const __hip_bfloat16*)Wht)[d * TWO_D + f]);
        whtp[i] = (half_t)v;
    }
    for (int i = gid; i < DPAD * KRL; i += gs) {
        int d = i / KRL, f = i - d * KRL;
        float v = 0.f;
        if (d < DD && f < DD)
            v = f32 ? ((const float*)Wrl)[d * DD + f]
                    : bf2f(((const __hip_bfloat16*)Wrl)[d * DD + f]);
        wrlp[i] = (half_t)v;
    }
    for (int i = gid; i < DPAD; i += gs) {
        float vh = 0.f, vr = 0.f;
        if (i < DD) {
            vh = f32 ? ((const float*)bht)[i] : bf2f(((const __hip_bfloat16*)bht)[i]);
            vr = f32 ? ((const float*)brl)[i] : bf2f(((const __hip_bfloat16*)brl)[i]);
        }
        bhtp[i] = vh;
        brlp[i] = vr;
    }
}

// ---------- streaming conversion: emb (fp32 or bf16) -> packed fp16 table in ws ----------
__global__ void conv_emb(const void* __restrict__ emb_raw, void* __restrict__ ws,
                         int nElems) {
    __shared__ int sflag;
    const int tid = threadIdx.x;
    if (tid < 64) {     // per-block local dtype detect (1 KB probe, L2-hot)
        int bad = 0;
        const unsigned int* embw = (const unsigned int*)emb_raw;
        #pragma unroll
        for (int i = 0; i < 4; i++) {
            unsigned int wv = embw[tid * 4 + i];
            unsigned int e0 = (wv >> 7)  & 0xFF;
            unsigned int e1 = (wv >> 23) & 0xFF;
            bad |= (e0 >= 0x87 || e1 >= 0x87) ? 1 : 0;
        }
        unsigned long long anyb = __ballot(bad != 0);
        if (tid == 0) sflag = anyb ? 1 : 0;
    }
    __syncthreads();
    const bool f32 = sflag != 0;

    half_t* tab = (half_t*)((char*)ws + WS_TAB);
    const int nChunks = nElems >> 2;                    // 4 elems per chunk
    const int gid = blockIdx.x * blockDim.x + tid;
    const int gs  = gridDim.x * blockDim.x;

    if (f32) {
        const float4* src = (const float4*)emb_raw;
        for (int c = gid; c < nChunks; c += gs) {
            float4 v = src[c];
            h4v h = { (half_t)v.x, (half_t)v.y, (half_t)v.z, (half_t)v.w };
            *(h4v*)(tab + 4 * c) = h;
        }
    } else {
        const uint2* src = (const uint2*)emb_raw;
        for (int c = gid; c < nChunks; c += gs) {
            uint2 u = src[c];
            h4v h = { (half_t)bfbits2f(u.x & 0xFFFF), (half_t)bfbits2f(u.x >> 16),
                      (half_t)bfbits2f(u.y & 0xFFFF), (half_t)bfbits2f(u.y >> 16) };
            *(h4v*)(tab + 4 * c) = h;
        }
    }
}

// ================= fast path: gather from fp16 table, LDS epilogue =================
__global__ __launch_bounds__(256, 4) void fused_fast(
    const int* __restrict__ ids,
    const void* __restrict__ ws,
    float* __restrict__ out) {
    __shared__ half_t sX[51 * XPITCH];   // rows 0..49 data, row 50 = zeros
    __shared__ int   sIds[KK * 3];
    __shared__ float sE[KK];
    __shared__ float sAl[KK];

    const int* flags = (const int*)ws;
    const half_t* tab  = (const half_t*)((const char*)ws + WS_TAB);
    const half_t* whtp = (const half_t*)((const char*)ws + WS_WHT);
    const half_t* wrlp = (const half_t*)((const char*)ws + WS_WRL);
    const float*  bhtp = (const float*)((const char*)ws + WS_BHT);
    const float*  brlp = (const float*)((const char*)ws + WS_BRL);

    const int tid = threadIdx.x;
    const int bt  = blockIdx.x;
    const int idsStride = flags[1] ? 2 : 1;

    if (tid < KK * 3) sIds[tid] = ids[(bt * (KK * 3) + tid) * idsStride];
    {
        unsigned int* sXw = (unsigned int*)sX;   // u32 pitch = 188
        for (int i = tid; i < 600; i += 256) {   // ht pad: elems [200,224)
            int r = i / 12, j = i - r * 12;
            sXw[r * 188 + 100 + j] = 0u;
        }
        for (int i = tid; i < 700; i += 256) {   // rl pad: elems [332,360)
            int r = i / 14, j = i - r * 14;
            sXw[r * 188 + 166 + j] = 0u;
        }
        for (int i = tid; i < 188; i += 256) sXw[50 * 188 + i] = 0u;
    }
    __syncthreads();

    // gather 150 fp16 rows (200 B each, exactly 4 HBM lines); 3750 8B-chunk tasks, 8+7 deep
    {
        uint2 va[8]; int dof[8];
        #pragma unroll
        for (int i = 0; i < 8; i++) {
            int c = tid + i * 256;
            int seg = c / 25, off = (c - seg * 25) * 4;
            int r = seg / 3, wh = seg - r * 3;   // 0=head 1=relation 2=tail
            size_t id = (size_t)sIds[seg];
            va[i]  = *(const uint2*)(tab + id * DD + off);
            dof[i] = r * XPITCH + ((wh == 1) ? (RLBASE + off) : ((wh ? DD : 0) + off));
        }
        #pragma unroll
        for (int i = 0; i < 8; i++) *(uint2*)(sX + dof[i]) = va[i];
        uint2 vb[7]; int dof2[7];
        #pragma unroll
        for (int i = 0; i < 7; i++) {
            int c = tid + (8 + i) * 256;
            bool ok = (c < KK * 3 * 25);
            int cc = ok ? c : 0;
            int seg = cc / 25, off = (cc - seg * 25) * 4;
            int r = seg / 3, wh = seg - r * 3;
            size_t id = (size_t)sIds[seg];
            if (ok) vb[i] = *(const uint2*)(tab + id * DD + off);
            dof2[i] = ok ? (r * XPITCH + ((wh == 1) ? (RLBASE + off) : ((wh ? DD : 0) + off))) : -1;
        }
        #pragma unroll
        for (int i = 0; i < 7; i++)
            if (dof2[i] >= 0) *(uint2*)(sX + dof2[i]) = vb[i];
    }
    __syncthreads();

    const int lane = tid & 63;
    const int w    = tid >> 6;
    const int n    = lane & 15;
    const int q    = lane >> 4;
    const int arow = w * 16 + n;
    const int arow2 = (arow < KK) ? arow : KK;   // clamp to zero row 50
    const half_t* abase = sX + arow2 * XPITCH;

    f32x4 accH[7];
    #pragma unroll
    for (int t = 0; t < 7; t++) {
        #pragma unroll
        for (int j = 0; j < 4; j++) accH[t][j] = 0.f;
    }
    #pragma unroll
    for (int ks = 0; ks < 7; ks++) {
        h8v a = *(const h8v*)(abase + ks * 32 + q * 8);
        #pragma unroll
        for (int nt = 0; nt < 7; nt++) {
            h8v b = *(const h8v*)(whtp + (nt * 16 + n) * KHT + ks * 32 + q * 8);
            accH[nt] = mfma16x16x32_f16(a, b, accH[nt]);
        }
    }

    float htv[7][4];
    #pragma unroll
    for (int nt = 0; nt < 7; nt++) {
        const float bias = bhtp[nt * 16 + n];
        #pragma unroll
        for (int j = 0; j < 4; j++) htv[nt][j] = tanh_fast(accH[nt][j] + bias);
    }

    f32x4 accR[7];
    #pragma unroll
    for (int t = 0; t < 7; t++) {
        #pragma unroll
        for (int j = 0; j < 4; j++) accR[t][j] = 0.f;
    }
    #pragma unroll
    for (int ks = 0; ks < 4; ks++) {
        h8v a = *(const h8v*)(abase + RLBASE + ks * 32 + q * 8);
        #pragma unroll
        for (int nt = 0; nt < 7; nt++) {
            h8v b = *(const h8v*)(wrlp + (nt * 16 + n) * KRL + ks * 32 + q * 8);
            accR[nt] = mfma16x16x32_f16(a, b, accR[nt]);
        }
    }

    float dj[4];
    #pragma unroll
    for (int j = 0; j < 4; j++) dj[j] = 0.f;
    #pragma unroll
    for (int nt = 0; nt < 7; nt++) {
        const float bias = brlp[nt * 16 + n];
        #pragma unroll
        for (int j = 0; j < 4; j++) dj[j] += (accR[nt][j] + bias) * htv[nt][j];
    }
    #pragma unroll
    for (int mask = 1; mask < 16; mask <<= 1) {
        #pragma unroll
        for (int j = 0; j < 4; j++) dj[j] += __shfl_xor(dj[j], mask, 64);
    }
    if (n == 0) {
        #pragma unroll
        for (int j = 0; j < 4; j++) {
            const int kt = w * 16 + q * 4 + j;   // C/D row = quad*4 + reg
            if (kt < KK) sE[kt] = dj[j];
        }
    }
    __syncthreads();

    if (tid < 64) {
        float v = -3.0e38f;
        if (tid < KK) v = sE[tid];
        float mx = v;
        #pragma unroll
        for (int mask = 1; mask < 64; mask <<= 1) mx = fmaxf(mx, __shfl_xor(mx, mask, 64));
        float p = (tid < KK) ? __expf(v - mx) : 0.f;
        float s = p;
        #pragma unroll
        for (int mask = 1; mask < 64; mask <<= 1) s += __shfl_xor(s, mask, 64);
        if (tid < KK) sAl[tid] = p / s;
    }
    __syncthreads();

    // epilogue straight from LDS fp16 (no global re-gather)
    if (tid < TWO_D) {
        float acc = 0.f;
        #pragma unroll 10
        for (int k = 0; k < KK; k++)
            acc += sAl[k] * (float)sX[k * XPITCH + tid];
        out[(size_t)bt * TWO_D + tid] = acc;
    }
}

// ============ fallback (ws too small): gather original emb, fp32 epilogue ============
__global__ __launch_bounds__(256, 4) void fused_fallback(
    const int* __restrict__ ids,
    const void* __restrict__ emb_raw,
    const void* __restrict__ ws,
    float* __restrict__ out) {
    __shared__ half_t sX[51 * XPITCH];
    __shared__ int   sIds[KK * 3];
    __shared__ float sE[KK];
    __shared__ float sAl[KK];

    const int* flags = (const int*)ws;
    const half_t* whtp = (const half_t*)((const char*)ws + WS_WHT);
    const half_t* wrlp = (const half_t*)((const char*)ws + WS_WRL);
    const float*  bhtp = (const float*)((const char*)ws + WS_BHT);
    const float*  brlp = (const float*)((const char*)ws + WS_BRL);

    const int tid = threadIdx.x;
    const int bt  = blockIdx.x;
    const bool f32      = flags[0] != 0;
    const int idsStride = flags[1] ? 2 : 1;

    if (tid < KK * 3) sIds[tid] = ids[(bt * (KK * 3) + tid) * idsStride];
    {
        unsigned int* sXw = (unsigned int*)sX;
        for (int i = tid; i < 600; i += 256) {
            int r = i / 12, j = i - r * 12;
            sXw[r * 188 + 100 + j] = 0u;
        }
        for (int i = tid; i < 700; i += 256) {
            int r = i / 14, j = i - r * 14;
            sXw[r * 188 + 166 + j] = 0u;
        }
        for (int i = tid; i < 188; i += 256) sXw[50 * 188 + i] = 0u;
    }
    __syncthreads();

    for (int c = tid; c < KK * 3 * 25; c += 256) {
        int seg = c / 25, off = (c - seg * 25) * 4;
        int r = seg / 3, wh = seg - r * 3;
        size_t id = (size_t)sIds[seg];
        half_t* dst = sX + r * XPITCH + ((wh == 1) ? (RLBASE + off) : ((wh ? DD : 0) + off));
        if (f32) {
            float4 v = *(const float4*)((const float*)emb_raw + id * DD + off);
            h4v pk = { (half_t)v.x, (half_t)v.y, (half_t)v.z, (half_t)v.w };
            *(h4v*)dst = pk;
        } else {
            uint2 u = *(const uint2*)((const __hip_bfloat16*)emb_raw + id * DD + off);
            h4v pk = { (half_t)bfbits2f(u.x & 0xFFFF), (half_t)bfbits2f(u.x >> 16),
                       (half_t)bfbits2f(u.y & 0xFFFF), (half_t)bfbits2f(u.y >> 16) };
            *(h4v*)dst = pk;
        }
    }
    __syncthreads();

    const int lane = tid & 63;
    const int w    = tid >> 6;
    const int n    = lane & 15;
    const int q    = lane >> 4;
    const int arow = w * 16 + n;
    const int arow2 = (arow < KK) ? arow : KK;
    const half_t* abase = sX + arow2 * XPITCH;

    f32x4 accH[7];
    #pragma unroll
    for (int t = 0; t < 7; t++) {
        #pragma unroll
        for (int j = 0; j < 4; j++) accH[t][j] = 0.f;
    }
    #pragma unroll
    for (int ks = 0; ks < 7; ks++) {
        h8v a = *(const h8v*)(abase + ks * 32 + q * 8);
        #pragma unroll
        for (int nt = 0; nt < 7; nt++) {
            h8v b = *(const h8v*)(whtp + (nt * 16 + n) * KHT + ks * 32 + q * 8);
            accH[nt] = mfma16x16x32_f16(a, b, accH[nt]);
        }
    }
    float htv[7][4];
    #pragma unroll
    for (int nt = 0; nt < 7; nt++) {
        const float bias = bhtp[nt * 16 + n];
        #pragma unroll
        for (int j = 0; j < 4; j++) htv[nt][j] = tanh_fast(accH[nt][j] + bias);
    }
    f32x4 accR[7];
    #pragma unroll
    for (int t = 0; t < 7; t++) {
        #pragma unroll
        for (int j = 0; j < 4; j++) accR[t][j] = 0.f;
    }
    #pragma unroll
    for (int ks = 0; ks < 4; ks++) {
        h8v a = *(const h8v*)(abase + RLBASE + ks * 32 + q * 8);
        #pragma unroll
        for (int nt = 0; nt < 7; nt++) {
            h8v b = *(const h8v*)(wrlp + (nt * 16 + n) * KRL + ks * 32 + q * 8);
            accR[nt] = mfma16x16x32_f16(a, b, accR[nt]);
        }
    }
    float dj[4];
    #pragma unroll
    for (int j = 0; j < 4; j++) dj[j] = 0.f;
    #pragma unroll
    for (int nt = 0; nt < 7; nt++) {
        const float bias = brlp[nt * 16 + n];
        #pragma unroll
        for (int j = 0; j < 4; j++) dj[j] += (accR[nt][j] + bias) * htv[nt][j];
    }
    #pragma unroll
    for (int mask = 1; mask < 16; mask <<= 1) {
        #pragma unroll
        for (int j = 0; j < 4; j++) dj[j] += __shfl_xor(dj[j], mask, 64);
    }
    if (n == 0) {
        #pragma unroll
        for (int j = 0; j < 4; j++) {
            const int kt = w * 16 + q * 4 + j;
            if (kt < KK) sE[kt] = dj[j];
        }
    }
    __syncthreads();

    if (tid < 64) {
        float v = -3.0e38f;
        if (tid < KK) v = sE[tid];
        float mx = v;
        #pragma unroll
        for (int mask = 1; mask < 64; mask <<= 1) mx = fmaxf(mx, __shfl_xor(mx, mask, 64));
        float p = (tid < KK) ? __expf(v - mx) : 0.f;
        float s = p;
        #pragma unroll
        for (int mask = 1; mask < 64; mask <<= 1) s += __shfl_xor(s, mask, 64);
        if (tid < KK) sAl[tid] = p / s;
    }
    __syncthreads();

    if (tid < TWO_D) {
        const int half_ = tid / DD;
        const int dmod  = tid - half_ * DD;
        const int whoff = half_ ? 2 : 0;
        float acc = 0.f;
        if (f32) {
            const float* embf = (const float*)emb_raw;
            #pragma unroll 10
            for (int k = 0; k < KK; k++) {
                size_t id = (size_t)sIds[k * 3 + whoff];
                acc += sAl[k] * embf[id * DD + dmod];
            }
        } else {
            const __hip_bfloat16* embh = (const __hip_bfloat16*)emb_raw;
            #pragma unroll 10
            for (int k = 0; k < KK; k++) {
                size_t id = (size_t)sIds[k * 3 + whoff];
                acc += sAl[k] * bf2f(embh[id * DD + dmod]);
            }
        }
        out[(size_t)bt * TWO_D + tid] = acc;
    }
}

extern "C" void kernel_launch(void* const* d_in, const int* in_sizes, int n_in,
                              void* d_out, int out_size, void* d_ws, size_t ws_size,
                              hipStream_t stream) {
    const int*  ids = (const int*)d_in[1];
    const void* emb = d_in[3];
    const void* Wht = d_in[4];
    const void* bht = d_in[5];
    const void* Wrl = d_in[6];
    const void* brl = d_in[7];
    float* out = (float*)d_out;

    const int nbt    = in_sizes[1] / (KK * 3);   // B*T blocks
    const int nElems = in_sizes[3];              // V*DD
    const size_t need = (size_t)WS_TAB + 2ull * (size_t)nElems;

    hipLaunchKernelGGL(prep_weights, dim3(64), dim3(256), 0, stream,
                       Wht, bht, Wrl, brl,
                       (const unsigned int*)emb, (const unsigned int*)ids, d_ws);
    if (ws_size >= need) {
        hipLaunchKernelGGL(conv_emb, dim3(2048), dim3(256), 0, stream,
                           emb, d_ws, nElems);
        hipLaunchKernelGGL(fused_fast, dim3(nbt), dim3(256), 0, stream,
                           ids, (const void*)d_ws, out);
    } else {
        hipLaunchKernelGGL(fused_fallback, dim3(nbt), dim3(256), 0, stream,
                           ids, emb, (const void*)d_ws, out);
    }
}